// Round 2
// baseline (933.552 us; speedup 1.0000x reference)
//
#include <hip/hip_runtime.h>
#include <stdint.h>

// Problem constants (B*L=8192 tokens, D=1024, H=2048, E=8 top-2, S=1 shared)
#define T_TOK 8192
#define DIMV  1024
#define HIDV  2048
#define NE    8
#define CAP   8192          // per-expert token list capacity
#define ASSIGN_TOT 24576    // 16384 routed rows + 8192 shared rows

typedef __attribute__((ext_vector_type(8))) short          bf16x8;
typedef __attribute__((ext_vector_type(4))) float          floatx4;

__device__ __forceinline__ unsigned short f2bf(float f) {
    union { float f; unsigned int i; } v; v.f = f;
    unsigned int i = v.i;
    return (unsigned short)((i + 0x7FFFu + ((i >> 16) & 1u)) >> 16);   // RNE
}

// async global->LDS, 16B/lane; lds base wave-uniform (HW adds lane*16)
__device__ __forceinline__ void gll16(const void* g, void* l) {
    __builtin_amdgcn_global_load_lds((const __attribute__((address_space(1))) void*)g,
                                     (__attribute__((address_space(3))) void*)l,
                                     16, 0, 0);
}

// ---------------------------------------------------------------- x convert
// fp32 [T][D] -> bf16 [T][D]
__global__ __launch_bounds__(256) void xconv_kernel(
    const float* __restrict__ src, unsigned short* __restrict__ dst)
{
    size_t i = ((size_t)blockIdx.x * 256 + threadIdx.x) * 4;
    float4 v = *(const float4*)(src + i);
    ushort4 o;
    o.x = f2bf(v.x); o.y = f2bf(v.y); o.z = f2bf(v.z); o.w = f2bf(v.w);
    *(ushort4*)(dst + i) = o;
}

// ---------------------------------------------------------------- router
// one wave per token: fp32 logits (matches np ref precision), top-2
// (lowest-index tie-break like lax.top_k), 2-way softmax in fp32
__global__ __launch_bounds__(256) void router_kernel(
    const float* __restrict__ x,     // [T][D] fp32
    const float* __restrict__ rwp,   // [E][D] fp32
    const float* __restrict__ biasp, // [E]    fp32
    int* __restrict__ cnt, int* __restrict__ tlist, float* __restrict__ wlist)
{
    const int t    = blockIdx.x * 4 + (threadIdx.x >> 6);
    const int lane = threadIdx.x & 63;
    const float* xr = x + (size_t)t * DIMV + lane * 16;
    float xf[16];
#pragma unroll
    for (int q = 0; q < 4; q++) {
        float4 v = *(const float4*)(xr + q * 4);
        xf[q*4+0] = v.x; xf[q*4+1] = v.y; xf[q*4+2] = v.z; xf[q*4+3] = v.w;
    }
    float acc[NE];
#pragma unroll
    for (int e = 0; e < NE; e++) {
        const float* wr = rwp + (size_t)e * DIMV + lane * 16;
        float s = 0.f;
#pragma unroll
        for (int q = 0; q < 4; q++) {
            float4 v = *(const float4*)(wr + q * 4);
            s += xf[q*4+0]*v.x + xf[q*4+1]*v.y + xf[q*4+2]*v.z + xf[q*4+3]*v.w;
        }
        acc[e] = s;
    }
#pragma unroll
    for (int e = 0; e < NE; e++)
#pragma unroll
        for (int off = 32; off; off >>= 1) acc[e] += __shfl_xor(acc[e], off, 64);

    if (lane == 0) {
        float lg[NE];
#pragma unroll
        for (int e = 0; e < NE; e++) lg[e] = acc[e] + biasp[e];
        int e0 = 0;
#pragma unroll
        for (int e = 1; e < NE; e++) if (lg[e] > lg[e0]) e0 = e;
        int e1 = (e0 == 0) ? 1 : 0;
#pragma unroll
        for (int e = 0; e < NE; e++) if (e != e0 && lg[e] > lg[e1]) e1 = e;
        float z  = __expf(lg[e1] - lg[e0]);    // lg[e1] <= lg[e0], safe
        float p0 = 1.f / (1.f + z);
        float p1 = z  / (1.f + z);
        int s0 = atomicAdd(cnt + e0, 1);
        tlist[e0 * CAP + s0] = t; wlist[e0 * CAP + s0] = p0;
        int s1 = atomicAdd(cnt + e1, 1);
        tlist[e1 * CAP + s1] = t; wlist[e1 * CAP + s1] = p1;
    }
}

__global__ void offsets_kernel(const int* __restrict__ cnt, int* __restrict__ goff)
{
    if (threadIdx.x == 0 && blockIdx.x == 0) {
        int s = 0;
        for (int e = 0; e < NE; e++) { goff[e] = s; s += cnt[e]; }
        goff[NE] = 16384;
    }
}

// ---------------------------------------------------------------- cvt+transpose
// src fp32 [z][R][C] -> dst bf16 [z][C][R]
__global__ __launch_bounds__(256) void ctrans_kernel(
    const float* __restrict__ src, unsigned short* __restrict__ dst,
    int R, int C)
{
    __shared__ unsigned short tile[64][65];
    const size_t mo = (size_t)blockIdx.z * R * C;
    const int c0 = blockIdx.x * 64, r0 = blockIdx.y * 64;
    const int cc = threadIdx.x & 63, rr = threadIdx.x >> 6;
#pragma unroll
    for (int i = 0; i < 16; i++) {
        int r = rr * 16 + i;
        tile[r][cc] = f2bf(src[mo + (size_t)(r0 + r) * C + (c0 + cc)]);
    }
    __syncthreads();
#pragma unroll
    for (int i = 0; i < 16; i++) {
        int c = rr * 16 + i;
        dst[mo + (size_t)(c0 + c) * R + (r0 + cc)] = tile[cc][c];
    }
}

// ---------------------------------------------------------------- up GEMM
// z = 0..7 routed experts (gathered rows), z = 8 shared (identity rows)
// BM=128 BN=64 BK=32; 4 waves 2x2, each 64x32; dual acc share A-frags
__global__ __launch_bounds__(256, 2) void up_gemm(
    const unsigned short* __restrict__ x,     // [T][D] bf16
    const unsigned short* __restrict__ w1t,   // [E][H][D] bf16 n-major
    const unsigned short* __restrict__ w3t,
    const unsigned short* __restrict__ sw1t,  // [H][D]
    const unsigned short* __restrict__ sw3t,
    const int* __restrict__ cnt, const int* __restrict__ goff,
    const int* __restrict__ tlist,
    unsigned short* __restrict__ hbuf)        // [ASSIGN_TOT][H] bf16
{
    const int g = blockIdx.z;
    int n_rows, row_off;
    const unsigned short *B1p, *B3p;
    if (g < NE) {
        n_rows = cnt[g]; row_off = goff[g];
        B1p = w1t + (size_t)g * HIDV * DIMV;
        B3p = w3t + (size_t)g * HIDV * DIMV;
    } else {
        n_rows = T_TOK; row_off = 16384;
        B1p = sw1t; B3p = sw3t;
    }
    const int m0 = blockIdx.y * 128;
    if (m0 >= n_rows) return;
    const int n0 = blockIdx.x * 64;

    __shared__ __align__(16) unsigned short Al[128 * 32];
    __shared__ __align__(16) unsigned short B1l[64 * 32];
    __shared__ __align__(16) unsigned short B3l[64 * 32];

    const int tid  = threadIdx.x;
    const int lane = tid & 63;
    const int wave = tid >> 6;
    const int r0   = tid >> 2;   // staging row 0..63
    const int ck   = tid & 3;    // 16B chunk in 64B row

    int tokA, tokB;
    if (g < NE) {
        int ra = m0 + r0, rb = m0 + 64 + r0;
        tokA = (ra < n_rows) ? tlist[g * CAP + ra] : 0;
        tokB = (rb < n_rows) ? tlist[g * CAP + rb] : 0;
    } else { tokA = m0 + r0; tokB = m0 + 64 + r0; }

    const unsigned short* gA0 = x + (size_t)tokA * DIMV + ck * 8;
    const unsigned short* gA1 = x + (size_t)tokB * DIMV + ck * 8;
    const unsigned short* gB1 = B1p + (size_t)(n0 + r0) * DIMV + ck * 8;
    const unsigned short* gB3 = B3p + (size_t)(n0 + r0) * DIMV + ck * 8;

    char* AlB0 = (char*)Al  + wave * 1024;
    char* AlB1 = (char*)Al  + 4096 + wave * 1024;
    char* B1B  = (char*)B1l + wave * 1024;
    char* B3B  = (char*)B3l + wave * 1024;

    const int wm = wave & 1, wn = wave >> 1;
    const int m16 = lane & 15, quad = lane >> 4;

    floatx4 accg[4][2] = {};
    floatx4 accu[4][2] = {};

    const unsigned short* Afp  = Al  + (wm * 64 + m16) * 32 + quad * 8;
    const unsigned short* B1fp = B1l + (wn * 32 + m16) * 32 + quad * 8;
    const unsigned short* B3fp = B3l + (wn * 32 + m16) * 32 + quad * 8;

    for (int k0 = 0; k0 < DIMV; k0 += 32) {
        __syncthreads();
        gll16(gA0 + k0, AlB0);
        gll16(gA1 + k0, AlB1);
        gll16(gB1 + k0, B1B);
        gll16(gB3 + k0, B3B);
        __syncthreads();
        bf16x8 af[4], b1f[2], b3f[2];
#pragma unroll
        for (int i = 0; i < 4; i++) af[i] = *(const bf16x8*)(Afp + i * 16 * 32);
#pragma unroll
        for (int j = 0; j < 2; j++) {
            b1f[j] = *(const bf16x8*)(B1fp + j * 16 * 32);
            b3f[j] = *(const bf16x8*)(B3fp + j * 16 * 32);
        }
#pragma unroll
        for (int i = 0; i < 4; i++)
#pragma unroll
            for (int j = 0; j < 2; j++) {
                accg[i][j] = __builtin_amdgcn_mfma_f32_16x16x32_bf16(af[i], b1f[j], accg[i][j], 0, 0, 0);
                accu[i][j] = __builtin_amdgcn_mfma_f32_16x16x32_bf16(af[i], b3f[j], accu[i][j], 0, 0, 0);
            }
    }

    // epilogue: h = silu(g)*u, bf16   (D layout: row=quad*4+reg, col=lane&15)
#pragma unroll
    for (int i = 0; i < 4; i++) {
#pragma unroll
        for (int ii = 0; ii < 4; ii++) {
            int r = m0 + wm * 64 + i * 16 + quad * 4 + ii;
            if (r < n_rows) {
#pragma unroll
                for (int j = 0; j < 2; j++) {
                    int col = n0 + wn * 32 + j * 16 + m16;
                    float gv = accg[i][j][ii], uv = accu[i][j][ii];
                    float s  = gv / (1.0f + __expf(-gv));
                    hbuf[(size_t)(row_off + r) * HIDV + col] = f2bf(s * uv);
                }
            }
        }
    }
}

// ---------------------------------------------------------------- down GEMM
// shared group (g==8) plain-stores fp32 into d_out (covers all T*D, kills
// the 0xAA poison); routed groups atomicAdd with router weight folded in.
__global__ __launch_bounds__(256, 2) void down_gemm(
    const unsigned short* __restrict__ hbuf,  // [ASSIGN_TOT][H] bf16
    const unsigned short* __restrict__ w2t,   // [E][D][H] bf16 n-major
    const unsigned short* __restrict__ sw2t,  // [D][H]
    const int* __restrict__ cnt, const int* __restrict__ goff,
    const int* __restrict__ tlist, const float* __restrict__ wlist,
    float* __restrict__ outp, int gbase)
{
    const int g = gbase + blockIdx.z;
    int n_rows, row_off;
    const unsigned short* Bp;
    if (g < NE) {
        n_rows = cnt[g]; row_off = goff[g];
        Bp = w2t + (size_t)g * DIMV * HIDV;
    } else {
        n_rows = T_TOK; row_off = 16384;
        Bp = sw2t;
    }
    const int m0 = blockIdx.y * 128;
    if (m0 >= n_rows) return;
    const int n0 = blockIdx.x * 64;

    __shared__ __align__(16) unsigned short Al[128 * 32];
    __shared__ __align__(16) unsigned short Bl[64 * 32];

    const int tid  = threadIdx.x;
    const int lane = tid & 63;
    const int wave = tid >> 6;
    const int r0   = tid >> 2;
    const int ck   = tid & 3;

    const unsigned short* gA0 = hbuf + (size_t)(row_off + m0 + r0) * HIDV + ck * 8;
    const unsigned short* gA1 = hbuf + (size_t)(row_off + m0 + 64 + r0) * HIDV + ck * 8;
    const unsigned short* gB  = Bp + (size_t)(n0 + r0) * HIDV + ck * 8;

    char* AlB0 = (char*)Al + wave * 1024;
    char* AlB1 = (char*)Al + 4096 + wave * 1024;
    char* BB   = (char*)Bl + wave * 1024;

    const int wm = wave & 1, wn = wave >> 1;
    const int m16 = lane & 15, quad = lane >> 4;

    floatx4 acc[4][2] = {};

    const unsigned short* Afp = Al + (wm * 64 + m16) * 32 + quad * 8;
    const unsigned short* Bfp = Bl + (wn * 32 + m16) * 32 + quad * 8;

    for (int k0 = 0; k0 < HIDV; k0 += 32) {
        __syncthreads();
        gll16(gA0 + k0, AlB0);
        gll16(gA1 + k0, AlB1);
        gll16(gB  + k0, BB);
        __syncthreads();
        bf16x8 af[4], bf[2];
#pragma unroll
        for (int i = 0; i < 4; i++) af[i] = *(const bf16x8*)(Afp + i * 16 * 32);
#pragma unroll
        for (int j = 0; j < 2; j++) bf[j] = *(const bf16x8*)(Bfp + j * 16 * 32);
#pragma unroll
        for (int i = 0; i < 4; i++)
#pragma unroll
            for (int j = 0; j < 2; j++)
                acc[i][j] = __builtin_amdgcn_mfma_f32_16x16x32_bf16(af[i], bf[j], acc[i][j], 0, 0, 0);
    }

#pragma unroll
    for (int i = 0; i < 4; i++) {
#pragma unroll
        for (int ii = 0; ii < 4; ii++) {
            int r = m0 + wm * 64 + i * 16 + quad * 4 + ii;
            if (r < n_rows) {
                int tok; float wgt;
                if (g < NE) { tok = tlist[g * CAP + r]; wgt = wlist[g * CAP + r]; }
                else        { tok = r;                  wgt = 1.0f; }
#pragma unroll
                for (int j = 0; j < 2; j++) {
                    int col = n0 + wn * 32 + j * 16 + m16;
                    float v = acc[i][j][ii] * wgt;
                    if (g < NE) atomicAdd(outp + (size_t)tok * DIMV + col, v);
                    else        outp[(size_t)tok * DIMV + col] = v;
                }
            }
        }
    }
}

// ---------------------------------------------------------------- launch
extern "C" void kernel_launch(void* const* d_in, const int* in_sizes, int n_in,
                              void* d_out, int out_size, void* d_ws, size_t ws_size,
                              hipStream_t stream)
{
    (void)in_sizes; (void)n_in; (void)out_size; (void)ws_size;
    const float* x    = (const float*)d_in[0];   // [T][D] fp32
    const float* rw   = (const float*)d_in[1];   // [E][D]
    const float* bias = (const float*)d_in[2];   // [E]
    const float* w1   = (const float*)d_in[3];   // [E][D][H]
    const float* w3   = (const float*)d_in[4];
    const float* w2   = (const float*)d_in[5];   // [E][H][D]
    const float* sw1  = (const float*)d_in[6];   // [1][D][H]
    const float* sw3  = (const float*)d_in[7];
    const float* sw2  = (const float*)d_in[8];   // [1][H][D]
    float* outp = (float*)d_out;                 // [T][D] fp32

    char* p = (char*)d_ws;
    auto alloc = [&](size_t b) { char* r = p; p += (b + 255) & ~(size_t)255; return r; };
    int*   cnt   = (int*)  alloc(64);
    int*   goffp = (int*)  alloc(64);
    int*   tlist = (int*)  alloc((size_t)NE * CAP * 4);
    float* wlist = (float*)alloc((size_t)NE * CAP * 4);
    unsigned short* xb   = (unsigned short*)alloc((size_t)T_TOK * DIMV * 2);
    unsigned short* hbuf = (unsigned short*)alloc((size_t)ASSIGN_TOT * HIDV * 2);
    unsigned short* w1t  = (unsigned short*)alloc((size_t)NE * HIDV * DIMV * 2);
    unsigned short* w3t  = (unsigned short*)alloc((size_t)NE * HIDV * DIMV * 2);
    unsigned short* w2t  = (unsigned short*)alloc((size_t)NE * DIMV * HIDV * 2);
    unsigned short* sw1t = (unsigned short*)alloc((size_t)HIDV * DIMV * 2);
    unsigned short* sw3t = (unsigned short*)alloc((size_t)HIDV * DIMV * 2);
    unsigned short* sw2t = (unsigned short*)alloc((size_t)DIMV * HIDV * 2);

    hipMemsetAsync(cnt, 0, 64, stream);

    dim3 blk(256);
    xconv_kernel<<<dim3((T_TOK * DIMV) / 1024), blk, 0, stream>>>(x, xb);
    ctrans_kernel<<<dim3(HIDV/64, DIMV/64, NE), blk, 0, stream>>>(w1, w1t, DIMV, HIDV);
    ctrans_kernel<<<dim3(HIDV/64, DIMV/64, NE), blk, 0, stream>>>(w3, w3t, DIMV, HIDV);
    ctrans_kernel<<<dim3(DIMV/64, HIDV/64, NE), blk, 0, stream>>>(w2, w2t, HIDV, DIMV);
    ctrans_kernel<<<dim3(HIDV/64, DIMV/64, 1),  blk, 0, stream>>>(sw1, sw1t, DIMV, HIDV);
    ctrans_kernel<<<dim3(HIDV/64, DIMV/64, 1),  blk, 0, stream>>>(sw3, sw3t, DIMV, HIDV);
    ctrans_kernel<<<dim3(DIMV/64, HIDV/64, 1),  blk, 0, stream>>>(sw2, sw2t, HIDV, DIMV);

    router_kernel<<<dim3(T_TOK/4), blk, 0, stream>>>(x, rw, bias, cnt, tlist, wlist);
    offsets_kernel<<<dim3(1), dim3(64), 0, stream>>>(cnt, goffp);

    up_gemm<<<dim3(HIDV/64, 64, 9), blk, 0, stream>>>(xb, w1t, w3t, sw1t, sw3t,
                                                      cnt, goffp, tlist, hbuf);
    // shared down first (plain stores initialize d_out), then routed (atomicAdd)
    down_gemm<<<dim3(DIMV/64, 64, 1), blk, 0, stream>>>(hbuf, w2t, sw2t, cnt, goffp,
                                                        tlist, wlist, outp, 8);
    down_gemm<<<dim3(DIMV/64, 64, 8), blk, 0, stream>>>(hbuf, w2t, sw2t, cnt, goffp,
                                                        tlist, wlist, outp, 0);
}

// Round 3
// 901.238 us; speedup vs baseline: 1.0359x; 1.0359x over previous
//
#include <hip/hip_runtime.h>
#include <stdint.h>

// Problem constants (B*L=8192 tokens, D=1024, H=2048, E=8 top-2, S=1 shared)
#define T_TOK 8192
#define DIMV  1024
#define HIDV  2048
#define NE    8
#define CAP   8192          // per-expert token list capacity
#define ASSIGN_TOT 24576    // 16384 routed rows + 8192 shared rows

typedef __attribute__((ext_vector_type(8))) short          bf16x8;
typedef __attribute__((ext_vector_type(8))) unsigned short u16x8;
typedef __attribute__((ext_vector_type(4))) float          floatx4;

__device__ __forceinline__ unsigned short f2bf(float f) {
    union { float f; unsigned int i; } v; v.f = f;
    unsigned int i = v.i;
    return (unsigned short)((i + 0x7FFFu + ((i >> 16) & 1u)) >> 16);   // RNE
}

// async global->LDS, 16B/lane; lds base wave-uniform (HW adds lane*16)
__device__ __forceinline__ void gll16(const void* g, void* l) {
    __builtin_amdgcn_global_load_lds((const __attribute__((address_space(1))) void*)g,
                                     (__attribute__((address_space(3))) void*)l,
                                     16, 0, 0);
}

// ---------------------------------------------------------------- router
// one wave per token: fp32 logits (matches np ref precision), top-2
// (lowest-index tie-break like lax.top_k), 2-way softmax in fp32.
// Also emits the bf16 copy of x (the row is already in registers).
__global__ __launch_bounds__(256) void router_kernel(
    const float* __restrict__ x,     // [T][D] fp32
    const float* __restrict__ rwp,   // [E][D] fp32
    const float* __restrict__ biasp, // [E]    fp32
    unsigned short* __restrict__ xb, // [T][D] bf16 out
    int* __restrict__ cnt, int* __restrict__ tlist, float* __restrict__ wlist)
{
    const int t    = blockIdx.x * 4 + (threadIdx.x >> 6);
    const int lane = threadIdx.x & 63;
    const float* xr = x + (size_t)t * DIMV + lane * 16;
    float xf[16];
#pragma unroll
    for (int q = 0; q < 4; q++) {
        float4 v = *(const float4*)(xr + q * 4);
        xf[q*4+0] = v.x; xf[q*4+1] = v.y; xf[q*4+2] = v.z; xf[q*4+3] = v.w;
    }
    // fused fp32 -> bf16 conversion of x
    {
        u16x8 o0, o1;
#pragma unroll
        for (int j = 0; j < 8; j++) { o0[j] = f2bf(xf[j]); o1[j] = f2bf(xf[8 + j]); }
        unsigned short* xo = xb + (size_t)t * DIMV + lane * 16;
        *(u16x8*)xo = o0;
        *(u16x8*)(xo + 8) = o1;
    }
    float acc[NE];
#pragma unroll
    for (int e = 0; e < NE; e++) {
        const float* wr = rwp + (size_t)e * DIMV + lane * 16;
        float s = 0.f;
#pragma unroll
        for (int q = 0; q < 4; q++) {
            float4 v = *(const float4*)(wr + q * 4);
            s += xf[q*4+0]*v.x + xf[q*4+1]*v.y + xf[q*4+2]*v.z + xf[q*4+3]*v.w;
        }
        acc[e] = s;
    }
#pragma unroll
    for (int e = 0; e < NE; e++)
#pragma unroll
        for (int off = 32; off; off >>= 1) acc[e] += __shfl_xor(acc[e], off, 64);

    if (lane == 0) {
        float lg[NE];
#pragma unroll
        for (int e = 0; e < NE; e++) lg[e] = acc[e] + biasp[e];
        int e0 = 0;
#pragma unroll
        for (int e = 1; e < NE; e++) if (lg[e] > lg[e0]) e0 = e;
        int e1 = (e0 == 0) ? 1 : 0;
#pragma unroll
        for (int e = 0; e < NE; e++) if (e != e0 && lg[e] > lg[e1]) e1 = e;
        float z  = __expf(lg[e1] - lg[e0]);    // lg[e1] <= lg[e0], safe
        float p0 = 1.f / (1.f + z);
        float p1 = z  / (1.f + z);
        int s0 = atomicAdd(cnt + e0, 1);
        tlist[e0 * CAP + s0] = t; wlist[e0 * CAP + s0] = p0;
        int s1 = atomicAdd(cnt + e1, 1);
        tlist[e1 * CAP + s1] = t; wlist[e1 * CAP + s1] = p1;
    }
}

__global__ void offsets_kernel(const int* __restrict__ cnt, int* __restrict__ goff)
{
    if (threadIdx.x == 0 && blockIdx.x == 0) {
        int s = 0;
        for (int e = 0; e < NE; e++) { goff[e] = s; s += cnt[e]; }
        goff[NE] = 16384;
    }
}

// ---------------------------------------------------------------- cvt+transpose
// fp32 [R][C] tile -> bf16 [C][R]; float4 loads, ushort8 (16B) stores,
// LDS tile padded to 66 shorts (conflict-free column gather).
template<int R, int C>
__device__ __forceinline__ void ctrans_body(
    const float* __restrict__ src, unsigned short* __restrict__ dstp,
    unsigned short (*tile)[66])
{
    const int c0 = blockIdx.x * 64, r0 = blockIdx.y * 64;
    const int tid = threadIdx.x;
    const int lr = tid >> 4;            // 0..15
    const int lc = (tid & 15) * 4;      // 0,4,..,60
#pragma unroll
    for (int i = 0; i < 4; i++) {
        int r = lr + 16 * i;
        float4 v = *(const float4*)(src + (size_t)(r0 + r) * C + (c0 + lc));
        ushort4 o; o.x = f2bf(v.x); o.y = f2bf(v.y); o.z = f2bf(v.z); o.w = f2bf(v.w);
        *(ushort4*)&tile[r][lc] = o;
    }
    __syncthreads();
    const int oc  = tid >> 3;           // 0..31
    const int orr = (tid & 7) * 8;      // 0..56
#pragma unroll
    for (int i = 0; i < 2; i++) {
        int c = oc + 32 * i;
        u16x8 tmp;
#pragma unroll
        for (int j = 0; j < 8; j++) tmp[j] = tile[orr + j][c];
        *(u16x8*)(dstp + (size_t)(c0 + c) * R + (r0 + orr)) = tmp;
    }
}

// z: 0..7 -> w1[e], 8..15 -> w3[e], 16 -> sw1, 17 -> sw3   (all [D][H] -> [H][D])
__global__ __launch_bounds__(256) void ctransA_kernel(
    const float* __restrict__ w1, const float* __restrict__ w3,
    const float* __restrict__ sw1, const float* __restrict__ sw3,
    unsigned short* __restrict__ w1t, unsigned short* __restrict__ w3t,
    unsigned short* __restrict__ sw1t, unsigned short* __restrict__ sw3t)
{
    __shared__ unsigned short tile[64][66];
    const int z = blockIdx.z;
    const float* src; unsigned short* dstp;
    if (z < 8)       { src = w1  + (size_t)z * DIMV * HIDV;      dstp = w1t + (size_t)z * DIMV * HIDV; }
    else if (z < 16) { src = w3  + (size_t)(z - 8) * DIMV * HIDV; dstp = w3t + (size_t)(z - 8) * DIMV * HIDV; }
    else if (z == 16){ src = sw1; dstp = sw1t; }
    else             { src = sw3; dstp = sw3t; }
    ctrans_body<DIMV, HIDV>(src, dstp, tile);
}

// z: 0..7 -> w2[e], 8 -> sw2   (all [H][D] -> [D][H])
__global__ __launch_bounds__(256) void ctransB_kernel(
    const float* __restrict__ w2, const float* __restrict__ sw2,
    unsigned short* __restrict__ w2t, unsigned short* __restrict__ sw2t)
{
    __shared__ unsigned short tile[64][66];
    const int z = blockIdx.z;
    const float* src; unsigned short* dstp;
    if (z < 8) { src = w2 + (size_t)z * HIDV * DIMV; dstp = w2t + (size_t)z * HIDV * DIMV; }
    else       { src = sw2; dstp = sw2t; }
    ctrans_body<HIDV, DIMV>(src, dstp, tile);
}

// ---------------------------------------------------------------- up GEMM
// z = 0..7 routed experts (gathered rows), z = 8 shared (identity rows)
// BM=128 BN=64 BK=32; 4 waves 2x2, each 64x32; dual acc share A-frags.
// LDS chunk XOR-swizzle: logical 16B chunk c of row r lives at physical
// chunk c ^ ((r>>1)&3) -> fragment ds_read_b128 is 2-way (free) not 8-way.
__global__ __launch_bounds__(256, 2) void up_gemm(
    const unsigned short* __restrict__ x,     // [T][D] bf16
    const unsigned short* __restrict__ w1t,   // [E][H][D] bf16 n-major
    const unsigned short* __restrict__ w3t,
    const unsigned short* __restrict__ sw1t,  // [H][D]
    const unsigned short* __restrict__ sw3t,
    const int* __restrict__ cnt, const int* __restrict__ goff,
    const int* __restrict__ tlist,
    unsigned short* __restrict__ hbuf)        // [ASSIGN_TOT][H] bf16
{
    const int g = blockIdx.z;
    int n_rows, row_off;
    const unsigned short *B1p, *B3p;
    if (g < NE) {
        n_rows = cnt[g]; row_off = goff[g];
        B1p = w1t + (size_t)g * HIDV * DIMV;
        B3p = w3t + (size_t)g * HIDV * DIMV;
    } else {
        n_rows = T_TOK; row_off = 16384;
        B1p = sw1t; B3p = sw3t;
    }
    const int m0 = blockIdx.y * 128;
    if (m0 >= n_rows) return;
    const int n0 = blockIdx.x * 64;

    __shared__ __align__(16) unsigned short Al[128 * 32];
    __shared__ __align__(16) unsigned short B1l[64 * 32];
    __shared__ __align__(16) unsigned short B3l[64 * 32];

    const int tid  = threadIdx.x;
    const int lane = tid & 63;
    const int wave = tid >> 6;
    const int r0   = tid >> 2;                  // staging row 0..63
    const int ck   = (tid & 3) ^ ((r0 >> 1) & 3); // swizzled 16B chunk

    int tokA, tokB;
    if (g < NE) {
        int ra = m0 + r0, rb = m0 + 64 + r0;
        tokA = (ra < n_rows) ? tlist[g * CAP + ra] : 0;
        tokB = (rb < n_rows) ? tlist[g * CAP + rb] : 0;
    } else { tokA = m0 + r0; tokB = m0 + 64 + r0; }

    const unsigned short* gA0 = x + (size_t)tokA * DIMV + ck * 8;
    const unsigned short* gA1 = x + (size_t)tokB * DIMV + ck * 8;
    const unsigned short* gB1 = B1p + (size_t)(n0 + r0) * DIMV + ck * 8;
    const unsigned short* gB3 = B3p + (size_t)(n0 + r0) * DIMV + ck * 8;

    char* AlB0 = (char*)Al  + wave * 1024;
    char* AlB1 = (char*)Al  + 4096 + wave * 1024;
    char* B1B  = (char*)B1l + wave * 1024;
    char* B3B  = (char*)B3l + wave * 1024;

    const int wm = wave & 1, wn = wave >> 1;
    const int m16 = lane & 15, quad = lane >> 4;
    const int sw  = (m16 >> 1) & 3;             // read-side chunk swizzle

    floatx4 accg[4][2] = {};
    floatx4 accu[4][2] = {};

    const unsigned short* Afp  = Al  + (wm * 64 + m16) * 32 + (quad ^ sw) * 8;
    const unsigned short* B1fp = B1l + (wn * 32 + m16) * 32 + (quad ^ sw) * 8;
    const unsigned short* B3fp = B3l + (wn * 32 + m16) * 32 + (quad ^ sw) * 8;

    for (int k0 = 0; k0 < DIMV; k0 += 32) {
        __syncthreads();
        gll16(gA0 + k0, AlB0);
        gll16(gA1 + k0, AlB1);
        gll16(gB1 + k0, B1B);
        gll16(gB3 + k0, B3B);
        __syncthreads();
        bf16x8 af[4], b1f[2], b3f[2];
#pragma unroll
        for (int i = 0; i < 4; i++) af[i] = *(const bf16x8*)(Afp + i * 16 * 32);
#pragma unroll
        for (int j = 0; j < 2; j++) {
            b1f[j] = *(const bf16x8*)(B1fp + j * 16 * 32);
            b3f[j] = *(const bf16x8*)(B3fp + j * 16 * 32);
        }
#pragma unroll
        for (int i = 0; i < 4; i++)
#pragma unroll
            for (int j = 0; j < 2; j++) {
                accg[i][j] = __builtin_amdgcn_mfma_f32_16x16x32_bf16(af[i], b1f[j], accg[i][j], 0, 0, 0);
                accu[i][j] = __builtin_amdgcn_mfma_f32_16x16x32_bf16(af[i], b3f[j], accu[i][j], 0, 0, 0);
            }
    }

    // epilogue: h = silu(g)*u, bf16   (D layout: row=quad*4+reg, col=lane&15)
#pragma unroll
    for (int i = 0; i < 4; i++) {
#pragma unroll
        for (int ii = 0; ii < 4; ii++) {
            int r = m0 + wm * 64 + i * 16 + quad * 4 + ii;
            if (r < n_rows) {
#pragma unroll
                for (int j = 0; j < 2; j++) {
                    int col = n0 + wn * 32 + j * 16 + m16;
                    float gv = accg[i][j][ii], uv = accu[i][j][ii];
                    float s  = gv / (1.0f + __expf(-gv));
                    hbuf[(size_t)(row_off + r) * HIDV + col] = f2bf(s * uv);
                }
            }
        }
    }
}

// ---------------------------------------------------------------- down GEMM
// shared group (g==8) plain-stores fp32 into d_out (covers all T*D, kills
// the 0xAA poison); routed groups atomicAdd with router weight folded in.
__global__ __launch_bounds__(256, 2) void down_gemm(
    const unsigned short* __restrict__ hbuf,  // [ASSIGN_TOT][H] bf16
    const unsigned short* __restrict__ w2t,   // [E][D][H] bf16 n-major
    const unsigned short* __restrict__ sw2t,  // [D][H]
    const int* __restrict__ cnt, const int* __restrict__ goff,
    const int* __restrict__ tlist, const float* __restrict__ wlist,
    float* __restrict__ outp, int gbase)
{
    const int g = gbase + blockIdx.z;
    int n_rows, row_off;
    const unsigned short* Bp;
    if (g < NE) {
        n_rows = cnt[g]; row_off = goff[g];
        Bp = w2t + (size_t)g * DIMV * HIDV;
    } else {
        n_rows = T_TOK; row_off = 16384;
        Bp = sw2t;
    }
    const int m0 = blockIdx.y * 128;
    if (m0 >= n_rows) return;
    const int n0 = blockIdx.x * 64;

    __shared__ __align__(16) unsigned short Al[128 * 32];
    __shared__ __align__(16) unsigned short Bl[64 * 32];

    const int tid  = threadIdx.x;
    const int lane = tid & 63;
    const int wave = tid >> 6;
    const int r0   = tid >> 2;
    const int ck   = (tid & 3) ^ ((r0 >> 1) & 3);

    const unsigned short* gA0 = hbuf + (size_t)(row_off + m0 + r0) * HIDV + ck * 8;
    const unsigned short* gA1 = hbuf + (size_t)(row_off + m0 + 64 + r0) * HIDV + ck * 8;
    const unsigned short* gB  = Bp + (size_t)(n0 + r0) * HIDV + ck * 8;

    char* AlB0 = (char*)Al + wave * 1024;
    char* AlB1 = (char*)Al + 4096 + wave * 1024;
    char* BB   = (char*)Bl + wave * 1024;

    const int wm = wave & 1, wn = wave >> 1;
    const int m16 = lane & 15, quad = lane >> 4;
    const int sw  = (m16 >> 1) & 3;

    floatx4 acc[4][2] = {};

    const unsigned short* Afp = Al + (wm * 64 + m16) * 32 + (quad ^ sw) * 8;
    const unsigned short* Bfp = Bl + (wn * 32 + m16) * 32 + (quad ^ sw) * 8;

    for (int k0 = 0; k0 < HIDV; k0 += 32) {
        __syncthreads();
        gll16(gA0 + k0, AlB0);
        gll16(gA1 + k0, AlB1);
        gll16(gB  + k0, BB);
        __syncthreads();
        bf16x8 af[4], bf[2];
#pragma unroll
        for (int i = 0; i < 4; i++) af[i] = *(const bf16x8*)(Afp + i * 16 * 32);
#pragma unroll
        for (int j = 0; j < 2; j++) bf[j] = *(const bf16x8*)(Bfp + j * 16 * 32);
#pragma unroll
        for (int i = 0; i < 4; i++)
#pragma unroll
            for (int j = 0; j < 2; j++)
                acc[i][j] = __builtin_amdgcn_mfma_f32_16x16x32_bf16(af[i], bf[j], acc[i][j], 0, 0, 0);
    }

#pragma unroll
    for (int i = 0; i < 4; i++) {
#pragma unroll
        for (int ii = 0; ii < 4; ii++) {
            int r = m0 + wm * 64 + i * 16 + quad * 4 + ii;
            if (r < n_rows) {
                int tok; float wgt;
                if (g < NE) { tok = tlist[g * CAP + r]; wgt = wlist[g * CAP + r]; }
                else        { tok = r;                  wgt = 1.0f; }
#pragma unroll
                for (int j = 0; j < 2; j++) {
                    int col = n0 + wn * 32 + j * 16 + m16;
                    float v = acc[i][j][ii] * wgt;
                    if (g < NE) atomicAdd(outp + (size_t)tok * DIMV + col, v);
                    else        outp[(size_t)tok * DIMV + col] = v;
                }
            }
        }
    }
}

// ---------------------------------------------------------------- launch
extern "C" void kernel_launch(void* const* d_in, const int* in_sizes, int n_in,
                              void* d_out, int out_size, void* d_ws, size_t ws_size,
                              hipStream_t stream)
{
    (void)in_sizes; (void)n_in; (void)out_size; (void)ws_size;
    const float* x    = (const float*)d_in[0];   // [T][D] fp32
    const float* rw   = (const float*)d_in[1];   // [E][D]
    const float* bias = (const float*)d_in[2];   // [E]
    const float* w1   = (const float*)d_in[3];   // [E][D][H]
    const float* w3   = (const float*)d_in[4];
    const float* w2   = (const float*)d_in[5];   // [E][H][D]
    const float* sw1  = (const float*)d_in[6];   // [1][D][H]
    const float* sw3  = (const float*)d_in[7];
    const float* sw2  = (const float*)d_in[8];   // [1][H][D]
    float* outp = (float*)d_out;                 // [T][D] fp32

    char* p = (char*)d_ws;
    auto alloc = [&](size_t b) { char* r = p; p += (b + 255) & ~(size_t)255; return r; };
    int*   cnt   = (int*)  alloc(64);
    int*   goffp = (int*)  alloc(64);
    int*   tlist = (int*)  alloc((size_t)NE * CAP * 4);
    float* wlist = (float*)alloc((size_t)NE * CAP * 4);
    unsigned short* xb   = (unsigned short*)alloc((size_t)T_TOK * DIMV * 2);
    unsigned short* hbuf = (unsigned short*)alloc((size_t)ASSIGN_TOT * HIDV * 2);
    unsigned short* w1t  = (unsigned short*)alloc((size_t)NE * HIDV * DIMV * 2);
    unsigned short* w3t  = (unsigned short*)alloc((size_t)NE * HIDV * DIMV * 2);
    unsigned short* w2t  = (unsigned short*)alloc((size_t)NE * DIMV * HIDV * 2);
    unsigned short* sw1t = (unsigned short*)alloc((size_t)HIDV * DIMV * 2);
    unsigned short* sw3t = (unsigned short*)alloc((size_t)HIDV * DIMV * 2);
    unsigned short* sw2t = (unsigned short*)alloc((size_t)DIMV * HIDV * 2);

    hipMemsetAsync(cnt, 0, 64, stream);

    dim3 blk(256);
    router_kernel<<<dim3(T_TOK/4), blk, 0, stream>>>(x, rw, bias, xb, cnt, tlist, wlist);
    ctransA_kernel<<<dim3(HIDV/64, DIMV/64, 18), blk, 0, stream>>>(w1, w3, sw1, sw3,
                                                                   w1t, w3t, sw1t, sw3t);
    ctransB_kernel<<<dim3(DIMV/64, HIDV/64, 9),  blk, 0, stream>>>(w2, sw2, w2t, sw2t);
    offsets_kernel<<<dim3(1), dim3(64), 0, stream>>>(cnt, goffp);

    up_gemm<<<dim3(HIDV/64, 64, 9), blk, 0, stream>>>(xb, w1t, w3t, sw1t, sw3t,
                                                      cnt, goffp, tlist, hbuf);
    // shared down first (plain stores initialize d_out), then routed (atomicAdd)
    down_gemm<<<dim3(DIMV/64, 64, 1), blk, 0, stream>>>(hbuf, w2t, sw2t, cnt, goffp,
                                                        tlist, wlist, outp, 8);
    down_gemm<<<dim3(DIMV/64, 64, 8), blk, 0, stream>>>(hbuf, w2t, sw2t, cnt, goffp,
                                                        tlist, wlist, outp, 0);
}

// Round 4
// 851.833 us; speedup vs baseline: 1.0959x; 1.0580x over previous
//
#include <hip/hip_runtime.h>
#include <stdint.h>

// Problem constants (B*L=8192 tokens, D=1024, H=2048, E=8 top-2, S=1 shared)
#define T_TOK 8192
#define DIMV  1024
#define HIDV  2048
#define NE    8
#define CAP   8192          // per-expert token list capacity (2^13)
#define ROUTED 16384        // total routed assignments
#define ASSIGN_TOT 24576    // routed + 8192 shared rows

typedef __attribute__((ext_vector_type(8))) short          bf16x8;
typedef __attribute__((ext_vector_type(8))) unsigned short u16x8;
typedef __attribute__((ext_vector_type(4))) float          floatx4;

__device__ __forceinline__ unsigned short f2bf(float f) {
    union { float f; unsigned int i; } v; v.f = f;
    unsigned int i = v.i;
    return (unsigned short)((i + 0x7FFFu + ((i >> 16) & 1u)) >> 16);   // RNE
}
__device__ __forceinline__ float bf2f(unsigned short u) {
    union { unsigned int i; float f; } v; v.i = ((unsigned int)u) << 16; return v.f;
}

// async global->LDS, 16B/lane; lds base wave-uniform (HW adds lane*16)
__device__ __forceinline__ void gll16(const void* g, void* l) {
    __builtin_amdgcn_global_load_lds((const __attribute__((address_space(1))) void*)g,
                                     (__attribute__((address_space(3))) void*)l,
                                     16, 0, 0);
}

// ---------------------------------------------------------------- router
// one wave per token: fp32 logits (matches np ref precision), top-2
// (lowest-index tie-break like lax.top_k), 2-way softmax in fp32.
// Emits bf16 x copy + per-expert token list + per-token (expert,slot)/weights.
__global__ __launch_bounds__(256) void router_kernel(
    const float* __restrict__ x,     // [T][D] fp32
    const float* __restrict__ rwp,   // [E][D] fp32
    const float* __restrict__ biasp, // [E]    fp32
    unsigned short* __restrict__ xb, // [T][D] bf16 out
    int* __restrict__ cnt, int* __restrict__ tlist,
    int* __restrict__ pos, float* __restrict__ pw)
{
    const int t    = blockIdx.x * 4 + (threadIdx.x >> 6);
    const int lane = threadIdx.x & 63;
    const float* xr = x + (size_t)t * DIMV + lane * 16;
    float xf[16];
#pragma unroll
    for (int q = 0; q < 4; q++) {
        float4 v = *(const float4*)(xr + q * 4);
        xf[q*4+0] = v.x; xf[q*4+1] = v.y; xf[q*4+2] = v.z; xf[q*4+3] = v.w;
    }
    {
        u16x8 o0, o1;
#pragma unroll
        for (int j = 0; j < 8; j++) { o0[j] = f2bf(xf[j]); o1[j] = f2bf(xf[8 + j]); }
        unsigned short* xo = xb + (size_t)t * DIMV + lane * 16;
        *(u16x8*)xo = o0;
        *(u16x8*)(xo + 8) = o1;
    }
    float acc[NE];
#pragma unroll
    for (int e = 0; e < NE; e++) {
        const float* wr = rwp + (size_t)e * DIMV + lane * 16;
        float s = 0.f;
#pragma unroll
        for (int q = 0; q < 4; q++) {
            float4 v = *(const float4*)(wr + q * 4);
            s += xf[q*4+0]*v.x + xf[q*4+1]*v.y + xf[q*4+2]*v.z + xf[q*4+3]*v.w;
        }
        acc[e] = s;
    }
#pragma unroll
    for (int e = 0; e < NE; e++)
#pragma unroll
        for (int off = 32; off; off >>= 1) acc[e] += __shfl_xor(acc[e], off, 64);

    if (lane == 0) {
        float lg[NE];
#pragma unroll
        for (int e = 0; e < NE; e++) lg[e] = acc[e] + biasp[e];
        int e0 = 0;
#pragma unroll
        for (int e = 1; e < NE; e++) if (lg[e] > lg[e0]) e0 = e;
        int e1 = (e0 == 0) ? 1 : 0;
#pragma unroll
        for (int e = 0; e < NE; e++) if (e != e0 && lg[e] > lg[e1]) e1 = e;
        float z  = __expf(lg[e1] - lg[e0]);    // lg[e1] <= lg[e0], safe
        float p0 = 1.f / (1.f + z);
        float p1 = z  / (1.f + z);
        int s0 = atomicAdd(cnt + e0, 1);
        tlist[e0 * CAP + s0] = t;
        int s1 = atomicAdd(cnt + e1, 1);
        tlist[e1 * CAP + s1] = t;
        pos[2 * t + 0] = e0 * CAP + s0;
        pos[2 * t + 1] = e1 * CAP + s1;
        pw[2 * t + 0] = p0;
        pw[2 * t + 1] = p1;
    }
}

// ---------------------------------------------------------------- cvt+transpose
// fp32 [R][C] tile -> bf16 [C][R]; float4 loads, ushort8 (16B) stores,
// LDS tile padded to 66 shorts (conflict-free column gather).
template<int R, int C>
__device__ __forceinline__ void ctrans_body(
    const float* __restrict__ src, unsigned short* __restrict__ dstp,
    unsigned short (*tile)[66])
{
    const int c0 = blockIdx.x * 64, r0 = blockIdx.y * 64;
    const int tid = threadIdx.x;
    const int lr = tid >> 4;            // 0..15
    const int lc = (tid & 15) * 4;      // 0,4,..,60
#pragma unroll
    for (int i = 0; i < 4; i++) {
        int r = lr + 16 * i;
        float4 v = *(const float4*)(src + (size_t)(r0 + r) * C + (c0 + lc));
        ushort4 o; o.x = f2bf(v.x); o.y = f2bf(v.y); o.z = f2bf(v.z); o.w = f2bf(v.w);
        *(ushort4*)&tile[r][lc] = o;
    }
    __syncthreads();
    const int oc  = tid >> 3;           // 0..31
    const int orr = (tid & 7) * 8;      // 0..56
#pragma unroll
    for (int i = 0; i < 2; i++) {
        int c = oc + 32 * i;
        u16x8 tmp;
#pragma unroll
        for (int j = 0; j < 8; j++) tmp[j] = tile[orr + j][c];
        *(u16x8*)(dstp + (size_t)(c0 + c) * R + (r0 + orr)) = tmp;
    }
}

// z: 0..7 w1[e], 8..15 w3[e], 16 sw1, 17 sw3  ([D][H] -> [H][D], x<32,y<16)
// z: 18..25 w2[e], 26 sw2                     ([H][D] -> [D][H], x<16,y<32)
__global__ __launch_bounds__(256) void ctrans_all(
    const float* __restrict__ w1, const float* __restrict__ w3,
    const float* __restrict__ sw1, const float* __restrict__ sw3,
    const float* __restrict__ w2, const float* __restrict__ sw2,
    unsigned short* __restrict__ w1t, unsigned short* __restrict__ w3t,
    unsigned short* __restrict__ sw1t, unsigned short* __restrict__ sw3t,
    unsigned short* __restrict__ w2t, unsigned short* __restrict__ sw2t)
{
    __shared__ unsigned short tile[64][66];
    const int z = blockIdx.z;
    if (z < 18) {
        if (blockIdx.y >= DIMV / 64) return;
        const float* src; unsigned short* dstp;
        if (z < 8)        { src = w1 + (size_t)z * DIMV * HIDV;       dstp = w1t + (size_t)z * DIMV * HIDV; }
        else if (z < 16)  { src = w3 + (size_t)(z - 8) * DIMV * HIDV; dstp = w3t + (size_t)(z - 8) * DIMV * HIDV; }
        else if (z == 16) { src = sw1; dstp = sw1t; }
        else              { src = sw3; dstp = sw3t; }
        ctrans_body<DIMV, HIDV>(src, dstp, tile);
    } else {
        if (blockIdx.x >= DIMV / 64) return;
        const float* src; unsigned short* dstp;
        if (z < 26) { src = w2 + (size_t)(z - 18) * HIDV * DIMV; dstp = w2t + (size_t)(z - 18) * HIDV * DIMV; }
        else        { src = sw2; dstp = sw2t; }
        ctrans_body<HIDV, DIMV>(src, dstp, tile);
    }
}

// ---------------------------------------------------------------- up GEMM
// z = 0..7 routed experts (gathered rows), z = 8 shared (identity rows)
// BM=128 BN=64 BK=32; 4 waves 2x2, each 64x32; dual acc (g,u) share A-frags.
// LDS chunk XOR-swizzle: chunk c of row r lives at c ^ ((r>>1)&3).
__global__ __launch_bounds__(256, 2) void up_gemm(
    const unsigned short* __restrict__ x,     // [T][D] bf16
    const unsigned short* __restrict__ w1t,   // [E][H][D] bf16 n-major
    const unsigned short* __restrict__ w3t,
    const unsigned short* __restrict__ sw1t,  // [H][D]
    const unsigned short* __restrict__ sw3t,
    const int* __restrict__ cnt, const int* __restrict__ tlist,
    unsigned short* __restrict__ hbuf)        // [ASSIGN_TOT][H] bf16
{
    const int g = blockIdx.z;
    int n_rows, row_off;
    const unsigned short *B1p, *B3p;
    if (g < NE) {
        row_off = 0;
        for (int e = 0; e < g; e++) row_off += cnt[e];
        n_rows = cnt[g];
        B1p = w1t + (size_t)g * HIDV * DIMV;
        B3p = w3t + (size_t)g * HIDV * DIMV;
    } else {
        n_rows = T_TOK; row_off = ROUTED;
        B1p = sw1t; B3p = sw3t;
    }
    const int m0 = blockIdx.y * 128;
    if (m0 >= n_rows) return;
    const int n0 = blockIdx.x * 64;

    __shared__ __align__(16) unsigned short Al[128 * 32];
    __shared__ __align__(16) unsigned short B1l[64 * 32];
    __shared__ __align__(16) unsigned short B3l[64 * 32];

    const int tid  = threadIdx.x;
    const int lane = tid & 63;
    const int wave = tid >> 6;
    const int r0   = tid >> 2;                    // staging row 0..63
    const int ck   = (tid & 3) ^ ((r0 >> 1) & 3); // swizzled 16B chunk

    int tokA, tokB;
    if (g < NE) {
        int ra = m0 + r0, rb = m0 + 64 + r0;
        tokA = (ra < n_rows) ? tlist[g * CAP + ra] : 0;
        tokB = (rb < n_rows) ? tlist[g * CAP + rb] : 0;
    } else { tokA = m0 + r0; tokB = m0 + 64 + r0; }

    const unsigned short* gA0 = x + (size_t)tokA * DIMV + ck * 8;
    const unsigned short* gA1 = x + (size_t)tokB * DIMV + ck * 8;
    const unsigned short* gB1 = B1p + (size_t)(n0 + r0) * DIMV + ck * 8;
    const unsigned short* gB3 = B3p + (size_t)(n0 + r0) * DIMV + ck * 8;

    char* AlB0 = (char*)Al  + wave * 1024;
    char* AlB1 = (char*)Al  + 4096 + wave * 1024;
    char* B1B  = (char*)B1l + wave * 1024;
    char* B3B  = (char*)B3l + wave * 1024;

    const int wm = wave & 1, wn = wave >> 1;
    const int m16 = lane & 15, quad = lane >> 4;
    const int sw  = (m16 >> 1) & 3;               // read-side chunk swizzle

    floatx4 accg[4][2] = {};
    floatx4 accu[4][2] = {};

    const unsigned short* Afp  = Al  + (wm * 64 + m16) * 32 + (quad ^ sw) * 8;
    const unsigned short* B1fp = B1l + (wn * 32 + m16) * 32 + (quad ^ sw) * 8;
    const unsigned short* B3fp = B3l + (wn * 32 + m16) * 32 + (quad ^ sw) * 8;

    for (int k0 = 0; k0 < DIMV; k0 += 32) {
        __syncthreads();
        gll16(gA0 + k0, AlB0);
        gll16(gA1 + k0, AlB1);
        gll16(gB1 + k0, B1B);
        gll16(gB3 + k0, B3B);
        __syncthreads();
        bf16x8 af[4], b1f[2], b3f[2];
#pragma unroll
        for (int i = 0; i < 4; i++) af[i] = *(const bf16x8*)(Afp + i * 16 * 32);
#pragma unroll
        for (int j = 0; j < 2; j++) {
            b1f[j] = *(const bf16x8*)(B1fp + j * 16 * 32);
            b3f[j] = *(const bf16x8*)(B3fp + j * 16 * 32);
        }
#pragma unroll
        for (int i = 0; i < 4; i++)
#pragma unroll
            for (int j = 0; j < 2; j++) {
                accg[i][j] = __builtin_amdgcn_mfma_f32_16x16x32_bf16(af[i], b1f[j], accg[i][j], 0, 0, 0);
                accu[i][j] = __builtin_amdgcn_mfma_f32_16x16x32_bf16(af[i], b3f[j], accu[i][j], 0, 0, 0);
            }
    }

    // epilogue: h = silu(g)*u, bf16   (D layout: row=quad*4+reg, col=lane&15)
#pragma unroll
    for (int i = 0; i < 4; i++) {
#pragma unroll
        for (int ii = 0; ii < 4; ii++) {
            int r = m0 + wm * 64 + i * 16 + quad * 4 + ii;
            if (r < n_rows) {
#pragma unroll
                for (int j = 0; j < 2; j++) {
                    int col = n0 + wn * 32 + j * 16 + m16;
                    float gv = accg[i][j][ii], uv = accu[i][j][ii];
                    float s  = gv / (1.0f + __expf(-gv));
                    hbuf[(size_t)(row_off + r) * HIDV + col] = f2bf(s * uv);
                }
            }
        }
    }
}

// ---------------------------------------------------------------- down GEMM
// m97 config: BM=128 BN=128 BK=32, 4 waves 2x2, wave tile 64x64 (4x4 frags).
// No atomics: per-assignment rows -> dbuf bf16 (weights applied in combine).
__global__ __launch_bounds__(256, 2) void down_gemm(
    const unsigned short* __restrict__ hbuf,  // [ASSIGN_TOT][H] bf16
    const unsigned short* __restrict__ w2t,   // [E][D][H] bf16 n-major
    const unsigned short* __restrict__ sw2t,  // [D][H]
    const int* __restrict__ cnt,
    unsigned short* __restrict__ dbuf)        // [ASSIGN_TOT][D] bf16
{
    const int g = blockIdx.z;
    int n_rows, row_off;
    const unsigned short* Bp;
    if (g < NE) {
        row_off = 0;
        for (int e = 0; e < g; e++) row_off += cnt[e];
        n_rows = cnt[g];
        Bp = w2t + (size_t)g * DIMV * HIDV;
    } else {
        n_rows = T_TOK; row_off = ROUTED;
        Bp = sw2t;
    }
    const int m0 = blockIdx.y * 128;
    if (m0 >= n_rows) return;
    const int n0 = blockIdx.x * 128;

    __shared__ __align__(16) unsigned short Al[128 * 32];
    __shared__ __align__(16) unsigned short Bl[128 * 32];

    const int tid  = threadIdx.x;
    const int lane = tid & 63;
    const int wave = tid >> 6;
    const int r0   = tid >> 2;
    const int ck   = (tid & 3) ^ ((r0 >> 1) & 3);

    const unsigned short* gA0 = hbuf + (size_t)(row_off + m0 + r0) * HIDV + ck * 8;
    const unsigned short* gA1 = gA0 + (size_t)64 * HIDV;
    const unsigned short* gB0 = Bp + (size_t)(n0 + r0) * HIDV + ck * 8;
    const unsigned short* gB1 = gB0 + (size_t)64 * HIDV;

    char* AlB0 = (char*)Al + wave * 1024;
    char* AlB1 = (char*)Al + 4096 + wave * 1024;
    char* BB0  = (char*)Bl + wave * 1024;
    char* BB1  = (char*)Bl + 4096 + wave * 1024;

    const int wm = wave & 1, wn = wave >> 1;
    const int m16 = lane & 15, quad = lane >> 4;
    const int sw  = (m16 >> 1) & 3;

    floatx4 acc[4][4] = {};

    const unsigned short* Afp = Al + (wm * 64 + m16) * 32 + (quad ^ sw) * 8;
    const unsigned short* Bfp = Bl + (wn * 64 + m16) * 32 + (quad ^ sw) * 8;

    for (int k0 = 0; k0 < HIDV; k0 += 32) {
        __syncthreads();
        gll16(gA0 + k0, AlB0);
        gll16(gA1 + k0, AlB1);
        gll16(gB0 + k0, BB0);
        gll16(gB1 + k0, BB1);
        __syncthreads();
        bf16x8 af[4], bf[4];
#pragma unroll
        for (int i = 0; i < 4; i++) af[i] = *(const bf16x8*)(Afp + i * 16 * 32);
#pragma unroll
        for (int j = 0; j < 4; j++) bf[j] = *(const bf16x8*)(Bfp + j * 16 * 32);
#pragma unroll
        for (int i = 0; i < 4; i++)
#pragma unroll
            for (int j = 0; j < 4; j++)
                acc[i][j] = __builtin_amdgcn_mfma_f32_16x16x32_bf16(af[i], bf[j], acc[i][j], 0, 0, 0);
    }

#pragma unroll
    for (int i = 0; i < 4; i++) {
#pragma unroll
        for (int ii = 0; ii < 4; ii++) {
            int r = m0 + wm * 64 + i * 16 + quad * 4 + ii;
            if (r < n_rows) {
                unsigned short* drow = dbuf + (size_t)(row_off + r) * DIMV;
#pragma unroll
                for (int j = 0; j < 4; j++) {
                    int col = n0 + wn * 64 + j * 16 + m16;
                    drow[col] = f2bf(acc[i][j][ii]);
                }
            }
        }
    }
}

// ---------------------------------------------------------------- combine
// out[t] = p0*dbuf[row(e0,s0)] + p1*dbuf[row(e1,s1)] + dbuf[ROUTED+t]
__global__ __launch_bounds__(256) void combine_kernel(
    const unsigned short* __restrict__ dbuf,
    const int* __restrict__ cnt, const int* __restrict__ pos,
    const float* __restrict__ pw, float* __restrict__ outp)
{
    const int tid = threadIdx.x;
    const int t = blockIdx.x * 2 + (tid >> 7);
    const int c = (tid & 127) * 8;
    int goff[NE];
    {
        int s = 0;
#pragma unroll
        for (int e = 0; e < NE; e++) { goff[e] = s; s += cnt[e]; }
    }
    const int p0 = pos[2 * t], p1 = pos[2 * t + 1];
    const float w0 = pw[2 * t], w1 = pw[2 * t + 1];
    const int r0 = goff[p0 >> 13] + (p0 & (CAP - 1));
    const int r1 = goff[p1 >> 13] + (p1 & (CAP - 1));
    const u16x8 v0 = *(const u16x8*)(dbuf + (size_t)r0 * DIMV + c);
    const u16x8 v1 = *(const u16x8*)(dbuf + (size_t)r1 * DIMV + c);
    const u16x8 vs = *(const u16x8*)(dbuf + (size_t)(ROUTED + t) * DIMV + c);
    float o[8];
#pragma unroll
    for (int j = 0; j < 8; j++)
        o[j] = w0 * bf2f(v0[j]) + w1 * bf2f(v1[j]) + bf2f(vs[j]);
    float* op = outp + (size_t)t * DIMV + c;
    *(float4*)op       = make_float4(o[0], o[1], o[2], o[3]);
    *(float4*)(op + 4) = make_float4(o[4], o[5], o[6], o[7]);
}

// ---------------------------------------------------------------- launch
extern "C" void kernel_launch(void* const* d_in, const int* in_sizes, int n_in,
                              void* d_out, int out_size, void* d_ws, size_t ws_size,
                              hipStream_t stream)
{
    (void)in_sizes; (void)n_in; (void)out_size; (void)ws_size;
    const float* x    = (const float*)d_in[0];   // [T][D] fp32
    const float* rw   = (const float*)d_in[1];   // [E][D]
    const float* bias = (const float*)d_in[2];   // [E]
    const float* w1   = (const float*)d_in[3];   // [E][D][H]
    const float* w3   = (const float*)d_in[4];
    const float* w2   = (const float*)d_in[5];   // [E][H][D]
    const float* sw1  = (const float*)d_in[6];   // [1][D][H]
    const float* sw3  = (const float*)d_in[7];
    const float* sw2  = (const float*)d_in[8];   // [1][H][D]
    float* outp = (float*)d_out;                 // [T][D] fp32

    char* p = (char*)d_ws;
    auto alloc = [&](size_t b) { char* r = p; p += (b + 255) & ~(size_t)255; return r; };
    int*   cnt   = (int*)  alloc(64);
    int*   tlist = (int*)  alloc((size_t)NE * CAP * 4);
    int*   pos   = (int*)  alloc((size_t)T_TOK * 2 * 4);
    float* pw    = (float*)alloc((size_t)T_TOK * 2 * 4);
    unsigned short* xb   = (unsigned short*)alloc((size_t)T_TOK * DIMV * 2);
    unsigned short* hbuf = (unsigned short*)alloc((size_t)ASSIGN_TOT * HIDV * 2);
    unsigned short* w1t  = (unsigned short*)alloc((size_t)NE * HIDV * DIMV * 2);
    unsigned short* w3t  = (unsigned short*)alloc((size_t)NE * HIDV * DIMV * 2);
    unsigned short* w2t  = (unsigned short*)alloc((size_t)NE * DIMV * HIDV * 2);
    unsigned short* sw1t = (unsigned short*)alloc((size_t)HIDV * DIMV * 2);
    unsigned short* sw3t = (unsigned short*)alloc((size_t)HIDV * DIMV * 2);
    unsigned short* sw2t = (unsigned short*)alloc((size_t)DIMV * HIDV * 2);
    // dbuf (48 MB) aliases w1t+w3t (64 MB): dead after up_gemm, before down_gemm
    unsigned short* dbuf = w1t;

    hipMemsetAsync(cnt, 0, 64, stream);

    dim3 blk(256);
    router_kernel<<<dim3(T_TOK/4), blk, 0, stream>>>(x, rw, bias, xb, cnt, tlist, pos, pw);
    ctrans_all<<<dim3(HIDV/64, HIDV/64, 27), blk, 0, stream>>>(w1, w3, sw1, sw3, w2, sw2,
                                                               w1t, w3t, sw1t, sw3t, w2t, sw2t);
    up_gemm<<<dim3(HIDV/64, 64, 9), blk, 0, stream>>>(xb, w1t, w3t, sw1t, sw3t,
                                                      cnt, tlist, hbuf);
    down_gemm<<<dim3(DIMV/128, 64, 9), blk, 0, stream>>>(hbuf, w2t, sw2t, cnt, dbuf);
    combine_kernel<<<dim3(T_TOK/2), blk, 0, stream>>>(dbuf, cnt, pos, pw, outp);
}